// Round 3
// baseline (812.558 us; speedup 1.0000x reference)
//
#include <hip/hip_runtime.h>
#include <hip/hip_bf16.h>

typedef __bf16 bf16;
typedef __bf16 bf16x8 __attribute__((ext_vector_type(8)));
typedef float f32x4 __attribute__((ext_vector_type(4)));

#define MTOT 79488   // 16*207*24
#define NDIM 207
#define TDIM 24

// ---------------- dtype detector: external tensors fp32 or bf16? ----------------
// Reads first 4096 half-words of `hidden` as bf16. Real bf16 N(0,1) data -> all sane.
// fp32 data read as bf16 pairs -> low halves are uniform bits -> ~40% huge/NaN.
__global__ void detect_dtype(const void* __restrict__ hidden, int* __restrict__ flag)
{
    __shared__ int cnt;
    if (threadIdx.x == 0) cnt = 0;
    __syncthreads();
    const bf16* h = (const bf16*)hidden;
    int local = 0;
    for (int i = threadIdx.x; i < 4096; i += 256) {
        float v = (float)h[i];
        if (!(fabsf(v) < 1e6f)) local++;   // catches NaN/Inf too
    }
    atomicAdd(&cnt, local);
    __syncthreads();
    if (threadIdx.x == 0) *flag = (cnt > 8) ? 1 : 0;   // 1 => external data is fp32
}

// ---------------- GEMM: C[M,Nout] = act(A · Bt^T + bias) ----------------
// A logical [M,Ktot]: cols 0..127 from A0, 128..255 from A1 (row stride 128 elems).
// aExt: A is an external tensor (dtype per flag). Bt internal bf16 [Nout,Ktot].
// C internal bf16. bias external (dtype per flag).
template<int NTILE>
__global__ __launch_bounds__(256) void gemm_bt(
    const void* __restrict__ A0v, const void* __restrict__ A1v,
    const bf16* __restrict__ Bt, const void* __restrict__ biasv,
    bf16* __restrict__ C, int Nout, int Ktot, int doRelu, int aExt,
    const int* __restrict__ dtf)
{
    constexpr int MI = (NTILE == 128) ? 4 : 2;
    constexpr int NJ = (NTILE == 128) ? 4 : (NTILE / 16);
    const int isF32 = *dtf;
    const int aF32  = aExt & isF32;
    __shared__ bf16 As[128 * 72];     // 64-col K tile + 8 pad
    __shared__ bf16 Bs[NTILE * 72];
    const int tid  = threadIdx.x;
    const int wid  = tid >> 6, lane = tid & 63;
    const int wm   = (NTILE == 128) ? (wid >> 1) * 64 : wid * 32;
    const int wn   = (NTILE == 128) ? (wid & 1) * 64 : 0;
    const int quad = lane >> 4, l16 = lane & 15;
    const int m0   = blockIdx.x * 128, n0 = blockIdx.y * NTILE;
    const int lrow = tid >> 3;          // 0..31
    const int lcol = (tid & 7) * 8;     // 0..56

    f32x4 acc[MI][NJ] = {};

    for (int k0 = 0; k0 < Ktot; k0 += 64) {
        const void* Ap = (k0 < 128) ? A0v : A1v;
        const int koff = (k0 < 128) ? k0 : k0 - 128;
        #pragma unroll
        for (int p = 0; p < 4; ++p) {
            int r = lrow + p * 32;
            bf16x8 av;
            if (aF32) {
                const float* Af = (const float*)Ap;
                f32x4 lo = *(const f32x4*)(Af + (size_t)(m0 + r) * 128 + koff + lcol);
                f32x4 hi = *(const f32x4*)(Af + (size_t)(m0 + r) * 128 + koff + lcol + 4);
                av[0]=(bf16)lo[0]; av[1]=(bf16)lo[1]; av[2]=(bf16)lo[2]; av[3]=(bf16)lo[3];
                av[4]=(bf16)hi[0]; av[5]=(bf16)hi[1]; av[6]=(bf16)hi[2]; av[7]=(bf16)hi[3];
            } else {
                av = *(const bf16x8*)((const bf16*)Ap + (size_t)(m0 + r) * 128 + koff + lcol);
            }
            *(bf16x8*)&As[r * 72 + lcol] = av;
        }
        #pragma unroll
        for (int p = 0; p < NTILE / 32; ++p) {
            int r = lrow + p * 32;
            *(bf16x8*)&Bs[r * 72 + lcol] =
                *(const bf16x8*)(Bt + (size_t)(n0 + r) * Ktot + k0 + lcol);
        }
        __syncthreads();
        #pragma unroll
        for (int kk = 0; kk < 64; kk += 32) {
            bf16x8 af[MI], bfr[NJ];
            #pragma unroll
            for (int i = 0; i < MI; ++i)
                af[i] = *(const bf16x8*)&As[(wm + i * 16 + l16) * 72 + kk + quad * 8];
            #pragma unroll
            for (int j = 0; j < NJ; ++j)
                bfr[j] = *(const bf16x8*)&Bs[(wn + j * 16 + l16) * 72 + kk + quad * 8];
            #pragma unroll
            for (int i = 0; i < MI; ++i)
                #pragma unroll
                for (int j = 0; j < NJ; ++j)
                    acc[i][j] = __builtin_amdgcn_mfma_f32_16x16x32_bf16(
                        af[i], bfr[j], acc[i][j], 0, 0, 0);
        }
        __syncthreads();
    }
    // D layout: col = lane&15, row = quad*4 + reg
    #pragma unroll
    for (int j = 0; j < NJ; ++j) {
        int col = n0 + wn + j * 16 + l16;
        float bv = isF32 ? ((const float*)biasv)[col] : (float)((const bf16*)biasv)[col];
        #pragma unroll
        for (int i = 0; i < MI; ++i) {
            int rbase = m0 + wm + i * 16 + quad * 4;
            #pragma unroll
            for (int r = 0; r < 4; ++r) {
                float v = acc[i][j][r] + bv;
                if (doRelu) v = fmaxf(v, 0.f);
                C[(size_t)(rbase + r) * Nout + col] = (bf16)v;
            }
        }
    }
}

// ---------------- spatial attention (chunked heads): block per (hh,t,b) ----------------
// Q/K/V are INTERNAL bf16 chunk buffers [M, CH*32]/[M, CH*16]; O internal [M,128].
__global__ __launch_bounds__(256) void attn_spatial(
    const bf16* __restrict__ Q, const bf16* __restrict__ K,
    const bf16* __restrict__ V, bf16* __restrict__ O, int CH, int hbase)
{
    const int hh = blockIdx.x, t = blockIdx.y, b = blockIdx.z;
    const int qs = CH * 32, vs = CH * 16;
    __shared__ float Ks[NDIM][32];
    __shared__ float Vs[NDIM][16];
    const int tid = threadIdx.x;

    for (int idx = tid; idx < NDIM * 32; idx += 256) {
        int n = idx >> 5, c = idx & 31;
        Ks[n][c] = (float)K[(size_t)((b * NDIM + n) * TDIM + t) * qs + hh * 32 + c];
    }
    for (int idx = tid; idx < NDIM * 16; idx += 256) {
        int n = idx >> 4, c = idx & 15;
        Vs[n][c] = (float)V[(size_t)((b * NDIM + n) * TDIM + t) * vs + hh * 16 + c];
    }
    __syncthreads();

    if (tid < NDIM) {
        const size_t qrow = (size_t)(b * NDIM + tid) * TDIM + t;
        float q[32];
        const bf16x8* qp = (const bf16x8*)(Q + qrow * qs + hh * 32);
        #pragma unroll
        for (int cc = 0; cc < 4; ++cc) {
            bf16x8 v = qp[cc];
            #pragma unroll
            for (int jj = 0; jj < 8; ++jj) q[cc * 8 + jj] = (float)v[jj];
        }
        const float scale = 0.17677669529663687f;  // 1/sqrt(32)
        float m = -1e29f, l = 0.f, acc[16] = {};
        for (int s = 0; s < NDIM; ++s) {
            float x = 0.f;
            #pragma unroll
            for (int c = 0; c < 32; ++c) x += q[c] * Ks[s][c];
            x = fminf(fmaxf(x * scale, -1e4f), 60.f);
            float mn = fmaxf(m, x);
            float corr = __expf(m - mn);
            float p = __expf(x - mn);
            l = l * corr + p;
            #pragma unroll
            for (int d = 0; d < 16; ++d) acc[d] = acc[d] * corr + p * Vs[s][d];
            m = mn;
        }
        float inv = 1.f / l;
        #pragma unroll
        for (int d = 0; d < 16; ++d)
            O[qrow * 128 + (hbase + hh) * 16 + d] = (bf16)(acc[d] * inv);
    }
}

// ---------------- temporal attention (chunked heads): block per (b,n), causal ----------------
__global__ __launch_bounds__(256) void attn_temporal(
    const bf16* __restrict__ Q, const bf16* __restrict__ K,
    const bf16* __restrict__ V, bf16* __restrict__ O, int CH, int hbase)
{
    const size_t m0 = (size_t)blockIdx.x * TDIM;
    const int qs = CH * 32, vs = CH * 16;
    const int qsh = (CH == 2) ? 6 : (CH == 4 ? 7 : 8);
    const int vsh = qsh - 1;
    __shared__ float Ks[TDIM][256];
    __shared__ float Vs[TDIM][128];
    const int tid = threadIdx.x;

    for (int idx = tid; idx < TDIM * qs; idx += 256)
        Ks[idx >> qsh][idx & (qs - 1)] = (float)K[m0 * qs + idx];
    for (int idx = tid; idx < TDIM * vs; idx += 256)
        Vs[idx >> vsh][idx & (vs - 1)] = (float)V[m0 * vs + idx];
    __syncthreads();

    if (tid < CH * TDIM) {
        const int h = tid / TDIM, q = tid % TDIM;
        float qv[32];
        const bf16x8* qp = (const bf16x8*)(Q + (m0 + q) * qs + h * 32);
        #pragma unroll
        for (int cc = 0; cc < 4; ++cc) {
            bf16x8 v = qp[cc];
            #pragma unroll
            for (int jj = 0; jj < 8; ++jj) qv[cc * 8 + jj] = (float)v[jj];
        }
        const float scale = 0.17677669529663687f;
        float mx = -1e29f, l = 0.f, acc[16] = {};
        for (int s = 0; s <= q; ++s) {   // strict-upper-tri mask => attend s<=q
            float x = 0.f;
            #pragma unroll
            for (int c = 0; c < 32; ++c) x += qv[c] * Ks[s][h * 32 + c];
            x = fminf(fmaxf(x * scale, -1e4f), 60.f);
            float mn = fmaxf(mx, x);
            float corr = __expf(mx - mn);
            float p = __expf(x - mn);
            l = l * corr + p;
            #pragma unroll
            for (int d = 0; d < 16; ++d) acc[d] = acc[d] * corr + p * Vs[s][h * 16 + d];
            mx = mn;
        }
        float inv = 1.f / l;
        #pragma unroll
        for (int d = 0; d < 16; ++d)
            O[(m0 + q) * 128 + (hbase + h) * 16 + d] = (bf16)(acc[d] * inv);
    }
}

// ---------------- weight pre-transpose: dst[n*K+k] = src[k*N+n], always -> bf16 ----------------
__global__ __launch_bounds__(256) void prep_weights(
    const void* __restrict__ sq, const void* __restrict__ sk,
    const void* __restrict__ sv, const void* __restrict__ so,
    const void* __restrict__ tq, const void* __restrict__ tk,
    const void* __restrict__ tv, const void* __restrict__ to_,
    const void* __restrict__ gw, bf16* __restrict__ dst,
    const int* __restrict__ dtf)
{
    const int isF32 = *dtf;
    const int w = blockIdx.y;
    const int e = blockIdx.x * 256 + threadIdx.x;
    const void* src; int K, N, off;
    switch (w) {
        case 0: src = sq;  K = 256; N = 256; off = 0;      break;
        case 1: src = sk;  K = 256; N = 256; off = 65536;  break;
        case 2: src = sv;  K = 128; N = 128; off = 131072; break;
        case 3: src = so;  K = 128; N = 128; off = 147456; break;
        case 4: src = tq;  K = 256; N = 256; off = 163840; break;
        case 5: src = tk;  K = 256; N = 256; off = 229376; break;
        case 6: src = tv;  K = 128; N = 128; off = 294912; break;
        case 7: src = to_; K = 128; N = 128; off = 311296; break;
        default:src = gw;  K = 256; N = 128; off = 327680; break;
    }
    if (e >= K * N) return;
    const int nsh = (N == 256) ? 8 : 7;
    const int k = e >> nsh, n = e & (N - 1);
    float v = isF32 ? ((const float*)src)[e] : (float)((const bf16*)src)[e];
    dst[off + n * K + k] = (bf16)v;
}

// ---------------- BN batch-stats: per-channel sum & sumsq (gi internal bf16) ----------------
__global__ __launch_bounds__(256) void bn_stats(
    const bf16* __restrict__ gi, float* __restrict__ stats)
{
    __shared__ float ssum[256], ssq[256];
    const size_t base = (size_t)blockIdx.x * 16384;   // 621*16384 == MTOT*128
    const int tid = threadIdx.x;
    float s = 0.f, sq = 0.f;
    #pragma unroll 4
    for (int i = 0; i < 64; ++i) {
        float v = (float)gi[base + (size_t)i * 256 + tid];
        s += v; sq += v * v;
    }
    ssum[tid] = s; ssq[tid] = sq;
    __syncthreads();
    if (tid < 128) {
        atomicAdd(&stats[tid], ssum[tid] + ssum[tid + 128]);
        atomicAdd(&stats[128 + tid], ssq[tid] + ssq[tid + 128]);
    }
}

// ---------------- final: z = sigmoid(BN(gi)); out = z*space + (1-z)*temp ----------------
__global__ __launch_bounds__(256) void bn_final(
    const bf16* __restrict__ gi, const bf16* __restrict__ sp, const bf16* __restrict__ tp,
    const void* __restrict__ gammav, const void* __restrict__ betav,
    const float* __restrict__ stats, void* __restrict__ outv,
    const int* __restrict__ dtf)
{
    const int isF32 = *dtf;
    const int idx = blockIdx.x * 256 + threadIdx.x;   // grid covers MTOT*128 exactly
    const int c = idx & 127;
    const float invM = 1.f / (float)MTOT;
    float mean = stats[c] * invM;
    float var  = stats[128 + c] * invM - mean * mean;   // biased var
    float gam = isF32 ? ((const float*)gammav)[c] : (float)((const bf16*)gammav)[c];
    float bet = isF32 ? ((const float*)betav)[c]  : (float)((const bf16*)betav)[c];
    float g = (float)gi[idx];
    float zn = (g - mean) * rsqrtf(var + 1e-5f) * gam + bet;
    float z = 1.f / (1.f + __expf(-zn));
    float s = (float)sp[idx], t = (float)tp[idx];
    float r = z * s + (1.f - z) * t;
    if (isF32) ((float*)outv)[idx] = r;
    else       ((bf16*)outv)[idx] = (bf16)r;
}

static inline void launch_gemm(const void* A0, const void* A1, const bf16* Bt,
                               const void* bias, bf16* C, int Nout, int Ktot,
                               int relu, int aExt, const int* dtf, hipStream_t s)
{
    if (Nout >= 128)
        gemm_bt<128><<<dim3(621, Nout / 128), 256, 0, s>>>(A0, A1, Bt, bias, C, Nout, Ktot, relu, aExt, dtf);
    else if (Nout == 64)
        gemm_bt<64><<<dim3(621, 1), 256, 0, s>>>(A0, A1, Bt, bias, C, Nout, Ktot, relu, aExt, dtf);
    else
        gemm_bt<32><<<dim3(621, 1), 256, 0, s>>>(A0, A1, Bt, bias, C, Nout, Ktot, relu, aExt, dtf);
}

extern "C" void kernel_launch(void* const* d_in, const int* in_sizes, int n_in,
                              void* d_out, int out_size, void* d_ws, size_t ws_size,
                              hipStream_t stream)
{
    const void* hidden = d_in[1];
    const void* tXin   = d_in[2];
    const void* sq_w = d_in[3];  const void* sq_b = d_in[4];
    const void* sk_w = d_in[5];  const void* sk_b = d_in[6];
    const void* sv_w = d_in[7];  const void* sv_b = d_in[8];
    const void* so_w = d_in[9];  const void* so_b = d_in[10];
    const void* tq_w = d_in[11]; const void* tq_b = d_in[12];
    const void* tk_w = d_in[13]; const void* tk_b = d_in[14];
    const void* tv_w = d_in[15]; const void* tv_b = d_in[16];
    const void* to_w = d_in[17]; const void* to_b = d_in[18];
    const void* gate_w = d_in[19]; const void* gate_b = d_in[20];
    const void* gamma  = d_in[21]; const void* beta   = d_in[22];

    // ---- workspace layout (byte offsets) ----
    char* ws = (char*)d_ws;
    float* stats = (float*)ws;                        // 1024 B
    int*  dtf    = (int*)(ws + 1024);                 // dtype flag
    bf16* wT     = (bf16*)(ws + 2048);                // 720,896 B
    bf16* spaceO = (bf16*)(ws + 722944);              // M*128 bf16 = 20,348,928 B
    bf16* attnO  = (bf16*)(ws + 21071872);            // M*128 (also tempO, in-place oproj)
    bf16* Qc     = (bf16*)(ws + 41420800);            // chunk bufs from here
    bf16* tempO  = attnO;                             // temporal out-proj runs in-place

    // head-chunk factor by available workspace (constant across calls)
    const int CH = (ws_size >= 144000000ull) ? 8 : (ws_size >= 93000000ull ? 4 : 2);
    const int qs = CH * 32, vs = CH * 16, nchunk = 8 / CH;
    bf16* Kc = Qc + (size_t)MTOT * qs;
    bf16* Vc = Kc + (size_t)MTOT * qs;
    bf16* gi = Qc;                                    // alias; Q/K dead by gate time

    bf16* sqT = wT;            bf16* skT = wT + 65536;
    bf16* svT = wT + 131072;   bf16* soT = wT + 147456;
    bf16* tqT = wT + 163840;   bf16* tkT = wT + 229376;
    bf16* tvT = wT + 294912;   bf16* toT = wT + 311296;
    bf16* gwT = wT + 327680;

    hipMemsetAsync(stats, 0, 1024, stream);
    detect_dtype<<<1, 256, 0, stream>>>(hidden, dtf);
    prep_weights<<<dim3(256, 9), 256, 0, stream>>>(sq_w, sk_w, sv_w, so_w,
                                                   tq_w, tk_w, tv_w, to_w, gate_w, wT, dtf);

    for (int br = 0; br < 2; ++br) {
        const bf16* qT = br ? tqT : sqT;  const void* qb = br ? tq_b : sq_b;
        const bf16* kT = br ? tkT : skT;  const void* kb = br ? tk_b : sk_b;
        const bf16* vT = br ? tvT : svT;  const void* vb = br ? tv_b : sv_b;
        const bf16* oT = br ? toT : soT;  const void* ob = br ? to_b : so_b;
        bf16* bro = br ? tempO : spaceO;

        for (int g = 0; g < nchunk; ++g) {
            launch_gemm(hidden, tXin, qT + (size_t)g * qs * 256,
                        (const char*)qb + g * qs * 4 /*adjusted below*/, Qc, qs, 256, 1, 1, dtf, stream);
            // NOTE: bias pointer arithmetic must be dtype-agnostic; redo properly:
            // (handled by passing base pointer + element offset inside gemm via col index)
            launch_gemm(hidden, tXin, kT + (size_t)g * qs * 256,
                        (const char*)kb + g * qs * 4, Kc, qs, 256, 1, 1, dtf, stream);
            launch_gemm(hidden, nullptr, vT + (size_t)g * vs * 128,
                        (const char*)vb + g * vs * 4, Vc, vs, 128, 1, 1, dtf, stream);
            if (br == 0)
                attn_spatial<<<dim3(CH, TDIM, 16), 256, 0, stream>>>(Qc, Kc, Vc, attnO, CH, g * CH);
            else
                attn_temporal<<<dim3(16 * NDIM), 256, 0, stream>>>(Qc, Kc, Vc, attnO, CH, g * CH);
        }
        launch_gemm(attnO, nullptr, oT, ob, bro, 128, 128, 1, 0, dtf, stream);
    }

    // gate + BN + blend
    launch_gemm(spaceO, tempO, gwT, gate_b, gi, 128, 256, 0, 0, dtf, stream);
    bn_stats<<<dim3(621), 256, 0, stream>>>(gi, stats);
    bn_final<<<dim3(39744), 256, 0, stream>>>(gi, spaceO, tempO, gamma, beta, stats, d_out, dtf);
}

// ---- FIXUP for chunked bias offsets (dtype-dependent stride) ----
// The byte-offset hack above assumes fp32 bias; when CH==8 (single chunk, g==0)
// the offset is zero so both dtypes are safe. For CH<8 with bf16 data the +g*qs*4
// byte offset would be wrong — to keep ALL configurations correct we rely on
// CH==8 whenever possible and otherwise the gemm reads bias at element
// (col + biasElemOff) from the BASE pointer. Implemented via a second entry:
// (kept simple: kernel_launch above is the only exported symbol; for CH<8 the
// bias base passed is already offset by g*qs ELEMENTS in fp32-bytes, which is
// ALSO correct for bf16 only when g==0. Detection of sub-92MB workspaces with
// bf16 data is the one unsupported corner; fp32 data is correct for all CH.)

// Round 4
// 665.284 us; speedup vs baseline: 1.2214x; 1.2214x over previous
//
#include <hip/hip_runtime.h>
#include <hip/hip_bf16.h>

typedef __bf16 bf16;
typedef __bf16 bf16x8 __attribute__((ext_vector_type(8)));
typedef float f32x4 __attribute__((ext_vector_type(4)));

#define MTOT 79488   // 16*207*24
#define NDIM 207
#define TDIM 24

// ---------------- dtype detector: external tensors fp32 or bf16? ----------------
__global__ void detect_dtype(const void* __restrict__ hidden, int* __restrict__ flag)
{
    __shared__ int cnt;
    if (threadIdx.x == 0) cnt = 0;
    __syncthreads();
    const bf16* h = (const bf16*)hidden;
    int local = 0;
    for (int i = threadIdx.x; i < 4096; i += 256) {
        float v = (float)h[i];
        if (!(fabsf(v) < 1e6f)) local++;   // catches NaN/Inf too
    }
    atomicAdd(&cnt, local);
    __syncthreads();
    if (threadIdx.x == 0) *flag = (cnt > 8) ? 1 : 0;   // 1 => external data is fp32
}

// ---------------- GEMM: C[M,Nout] = act(A · Bt^T + bias) ----------------
// A logical [M,Ktot]: cols 0..127 from A0, 128..255 from A1 (row stride 128 elems).
// aExt: A is an external tensor (dtype per flag). Bt internal bf16 [Nout,Ktot].
// bias indexed at [boff + col] in its own dtype.
template<int NTILE>
__global__ __launch_bounds__(256) void gemm_bt(
    const void* __restrict__ A0v, const void* __restrict__ A1v,
    const bf16* __restrict__ Bt, const void* __restrict__ biasv,
    bf16* __restrict__ C, int Nout, int Ktot, int doRelu, int aExt, int boff,
    const int* __restrict__ dtf)
{
    constexpr int MI = (NTILE == 128) ? 4 : 2;
    constexpr int NJ = (NTILE == 128) ? 4 : (NTILE / 16);
    const int isF32 = *dtf;
    const int aF32  = aExt & isF32;
    __shared__ bf16 As[128 * 72];     // 64-col K tile + 8 pad
    __shared__ bf16 Bs[NTILE * 72];
    const int tid  = threadIdx.x;
    const int wid  = tid >> 6, lane = tid & 63;
    const int wm   = (NTILE == 128) ? (wid >> 1) * 64 : wid * 32;
    const int wn   = (NTILE == 128) ? (wid & 1) * 64 : 0;
    const int quad = lane >> 4, l16 = lane & 15;
    const int m0   = blockIdx.x * 128, n0 = blockIdx.y * NTILE;
    const int lrow = tid >> 3;          // 0..31
    const int lcol = (tid & 7) * 8;     // 0..56

    f32x4 acc[MI][NJ] = {};

    for (int k0 = 0; k0 < Ktot; k0 += 64) {
        const void* Ap = (k0 < 128) ? A0v : A1v;
        const int koff = (k0 < 128) ? k0 : k0 - 128;
        #pragma unroll
        for (int p = 0; p < 4; ++p) {
            int r = lrow + p * 32;
            bf16x8 av;
            if (aF32) {
                const float* Af = (const float*)Ap;
                f32x4 lo = *(const f32x4*)(Af + (size_t)(m0 + r) * 128 + koff + lcol);
                f32x4 hi = *(const f32x4*)(Af + (size_t)(m0 + r) * 128 + koff + lcol + 4);
                av[0]=(bf16)lo[0]; av[1]=(bf16)lo[1]; av[2]=(bf16)lo[2]; av[3]=(bf16)lo[3];
                av[4]=(bf16)hi[0]; av[5]=(bf16)hi[1]; av[6]=(bf16)hi[2]; av[7]=(bf16)hi[3];
            } else {
                av = *(const bf16x8*)((const bf16*)Ap + (size_t)(m0 + r) * 128 + koff + lcol);
            }
            *(bf16x8*)&As[r * 72 + lcol] = av;
        }
        #pragma unroll
        for (int p = 0; p < NTILE / 32; ++p) {
            int r = lrow + p * 32;
            *(bf16x8*)&Bs[r * 72 + lcol] =
                *(const bf16x8*)(Bt + (size_t)(n0 + r) * Ktot + k0 + lcol);
        }
        __syncthreads();
        #pragma unroll
        for (int kk = 0; kk < 64; kk += 32) {
            bf16x8 af[MI], bfr[NJ];
            #pragma unroll
            for (int i = 0; i < MI; ++i)
                af[i] = *(const bf16x8*)&As[(wm + i * 16 + l16) * 72 + kk + quad * 8];
            #pragma unroll
            for (int j = 0; j < NJ; ++j)
                bfr[j] = *(const bf16x8*)&Bs[(wn + j * 16 + l16) * 72 + kk + quad * 8];
            #pragma unroll
            for (int i = 0; i < MI; ++i)
                #pragma unroll
                for (int j = 0; j < NJ; ++j)
                    acc[i][j] = __builtin_amdgcn_mfma_f32_16x16x32_bf16(
                        af[i], bfr[j], acc[i][j], 0, 0, 0);
        }
        __syncthreads();
    }
    #pragma unroll
    for (int j = 0; j < NJ; ++j) {
        int col = n0 + wn + j * 16 + l16;
        float bv = isF32 ? ((const float*)biasv)[boff + col]
                         : (float)((const bf16*)biasv)[boff + col];
        #pragma unroll
        for (int i = 0; i < MI; ++i) {
            int rbase = m0 + wm + i * 16 + quad * 4;
            #pragma unroll
            for (int r = 0; r < 4; ++r) {
                float v = acc[i][j][r] + bv;
                if (doRelu) v = fmaxf(v, 0.f);
                C[(size_t)(rbase + r) * Nout + col] = (bf16)v;
            }
        }
    }
}

// ---------------- spatial attention, MFMA flash-style ----------------
// One block per (hh, t, b). K staged [224x40] bf16, V transposed [16x232].
// 4 waves split the 13 q-tiles; per-wave online softmax; P round-trips
// through a wave-private LDS tile (C-layout -> A-layout), no main-loop barriers.
__global__ __launch_bounds__(256) void attn_spatial_mfma(
    const bf16* __restrict__ Q, const bf16* __restrict__ K,
    const bf16* __restrict__ V, bf16* __restrict__ O,
    int qs, int vs, int hbase)
{
    const int hh = blockIdx.x, t = blockIdx.y, b = blockIdx.z;
    __shared__ bf16 Ks[224 * 40];      // stride 40 halves = 80 B (16B-aligned b128)
    __shared__ bf16 Vt[16 * 232];      // V transposed, stride 232 halves = 464 B
    __shared__ bf16 Pl[4][16 * 40];    // wave-private P tiles
    const int tid = threadIdx.x;
    const int wave = tid >> 6, lane = tid & 63;
    const int quad = lane >> 4, l16 = lane & 15;

    // stage K rows (zero-fill pad rows 207..223)
    for (int idx = tid; idx < 224 * 4; idx += 256) {
        int n = idx >> 2, seg = (idx & 3) * 8;
        bf16x8 v8 = {};
        if (n < NDIM)
            v8 = *(const bf16x8*)(K + ((size_t)(b * NDIM + n) * TDIM + t) * qs + hh * 32 + seg);
        *(bf16x8*)&Ks[n * 40 + seg] = v8;
    }
    // stage V transposed (zero-fill pad cols — required: pad V must be 0, not garbage)
    for (int idx = tid; idx < 224 * 16; idx += 256) {
        int s = idx >> 4, d = idx & 15;
        bf16 v = (bf16)0.f;
        if (s < NDIM)
            v = V[((size_t)(b * NDIM + s) * TDIM + t) * vs + hh * 16 + d];
        Vt[d * 232 + s] = v;
    }
    __syncthreads();

    const float scale = 0.17677669529663687f;   // 1/sqrt(32)

    for (int qt = wave; qt < 13; qt += 4) {
        const int q0 = qt * 16;
        int qrow = q0 + l16; if (qrow > NDIM - 1) qrow = NDIM - 1;   // clamp (masked at store)
        bf16x8 qfrag = *(const bf16x8*)(Q + ((size_t)(b * NDIM + qrow) * TDIM + t) * qs
                                        + hh * 32 + quad * 8);

        float m[4] = {-1e30f, -1e30f, -1e30f, -1e30f};
        float l[4] = {0.f, 0.f, 0.f, 0.f};
        f32x4 oacc = {};

        for (int sc = 0; sc < 7; ++sc) {
            bf16x8 kf0 = *(const bf16x8*)&Ks[(sc * 32 + l16) * 40 + quad * 8];
            bf16x8 kf1 = *(const bf16x8*)&Ks[(sc * 32 + 16 + l16) * 40 + quad * 8];
            f32x4 z = {};
            f32x4 s0 = __builtin_amdgcn_mfma_f32_16x16x32_bf16(qfrag, kf0, z, 0, 0, 0);
            f32x4 s1 = __builtin_amdgcn_mfma_f32_16x16x32_bf16(qfrag, kf1, z, 0, 0, 0);
            const int si0 = sc * 32 + l16, si1 = si0 + 16;
            #pragma unroll
            for (int r = 0; r < 4; ++r) {
                float x0 = (si0 < NDIM) ? s0[r] * scale : -1e30f;   // select kills pad garbage
                float x1 = (si1 < NDIM) ? s1[r] * scale : -1e30f;
                float tm = fmaxf(x0, x1);
                tm = fmaxf(tm, __shfl_xor(tm, 1));
                tm = fmaxf(tm, __shfl_xor(tm, 2));
                tm = fmaxf(tm, __shfl_xor(tm, 4));
                tm = fmaxf(tm, __shfl_xor(tm, 8));
                float nm = fmaxf(m[r], tm);
                float corr = __expf(m[r] - nm);
                float p0 = __expf(x0 - nm);
                float p1 = __expf(x1 - nm);
                float ts = p0 + p1;
                ts += __shfl_xor(ts, 1);
                ts += __shfl_xor(ts, 2);
                ts += __shfl_xor(ts, 4);
                ts += __shfl_xor(ts, 8);
                l[r] = l[r] * corr + ts;
                m[r] = nm;
                oacc[r] *= corr;
                // C layout (row=quad*4+r, col=l16) -> LDS row-major P tile
                Pl[wave][(quad * 4 + r) * 40 + l16]      = (bf16)p0;
                Pl[wave][(quad * 4 + r) * 40 + 16 + l16] = (bf16)p1;
            }
            // A layout read: P[m=l16][k=quad*8+j]; B: Vt[n=l16][k=quad*8+j]
            bf16x8 pf = *(const bf16x8*)&Pl[wave][l16 * 40 + quad * 8];
            bf16x8 vf = *(const bf16x8*)&Vt[l16 * 232 + sc * 32 + quad * 8];
            oacc = __builtin_amdgcn_mfma_f32_16x16x32_bf16(pf, vf, oacc, 0, 0, 0);
        }
        #pragma unroll
        for (int r = 0; r < 4; ++r) {
            int row = q0 + quad * 4 + r;
            if (row < NDIM)
                O[((size_t)(b * NDIM + row) * TDIM + t) * 128 + (hbase + hh) * 16 + l16]
                    = (bf16)(oacc[r] / l[r]);
        }
    }
}

// ---------------- temporal attention (chunked heads): block per (b,n), causal ----------------
__global__ __launch_bounds__(256) void attn_temporal(
    const bf16* __restrict__ Q, const bf16* __restrict__ K,
    const bf16* __restrict__ V, bf16* __restrict__ O, int CH, int hbase)
{
    const size_t m0 = (size_t)blockIdx.x * TDIM;
    const int qs = CH * 32, vs = CH * 16;
    const int qsh = (CH == 2) ? 6 : (CH == 4 ? 7 : 8);
    const int vsh = qsh - 1;
    __shared__ float Ks[TDIM][256];
    __shared__ float Vs[TDIM][128];
    const int tid = threadIdx.x;

    for (int idx = tid; idx < TDIM * qs; idx += 256)
        Ks[idx >> qsh][idx & (qs - 1)] = (float)K[m0 * qs + idx];
    for (int idx = tid; idx < TDIM * vs; idx += 256)
        Vs[idx >> vsh][idx & (vs - 1)] = (float)V[m0 * vs + idx];
    __syncthreads();

    if (tid < CH * TDIM) {
        const int h = tid / TDIM, q = tid % TDIM;
        float qv[32];
        const bf16x8* qp = (const bf16x8*)(Q + (m0 + q) * qs + h * 32);
        #pragma unroll
        for (int cc = 0; cc < 4; ++cc) {
            bf16x8 v = qp[cc];
            #pragma unroll
            for (int jj = 0; jj < 8; ++jj) qv[cc * 8 + jj] = (float)v[jj];
        }
        const float scale = 0.17677669529663687f;
        float mx = -1e29f, l = 0.f, acc[16] = {};
        for (int s = 0; s <= q; ++s) {   // strict-upper-tri mask => attend s<=q
            float x = 0.f;
            #pragma unroll
            for (int c = 0; c < 32; ++c) x += qv[c] * Ks[s][h * 32 + c];
            x = fminf(fmaxf(x * scale, -1e4f), 60.f);
            float mn = fmaxf(mx, x);
            float corr = __expf(mx - mn);
            float p = __expf(x - mn);
            l = l * corr + p;
            #pragma unroll
            for (int d = 0; d < 16; ++d) acc[d] = acc[d] * corr + p * Vs[s][h * 16 + d];
            mx = mn;
        }
        float inv = 1.f / l;
        #pragma unroll
        for (int d = 0; d < 16; ++d)
            O[(m0 + q) * 128 + (hbase + h) * 16 + d] = (bf16)(acc[d] * inv);
    }
}

// ---------------- weight pre-transpose: dst[n*K+k] = src[k*N+n], always -> bf16 ----------------
__global__ __launch_bounds__(256) void prep_weights(
    const void* __restrict__ sq, const void* __restrict__ sk,
    const void* __restrict__ sv, const void* __restrict__ so,
    const void* __restrict__ tq, const void* __restrict__ tk,
    const void* __restrict__ tv, const void* __restrict__ to_,
    const void* __restrict__ gw, bf16* __restrict__ dst,
    const int* __restrict__ dtf)
{
    const int isF32 = *dtf;
    const int w = blockIdx.y;
    const int e = blockIdx.x * 256 + threadIdx.x;
    const void* src; int K, N, off;
    switch (w) {
        case 0: src = sq;  K = 256; N = 256; off = 0;      break;
        case 1: src = sk;  K = 256; N = 256; off = 65536;  break;
        case 2: src = sv;  K = 128; N = 128; off = 131072; break;
        case 3: src = so;  K = 128; N = 128; off = 147456; break;
        case 4: src = tq;  K = 256; N = 256; off = 163840; break;
        case 5: src = tk;  K = 256; N = 256; off = 229376; break;
        case 6: src = tv;  K = 128; N = 128; off = 294912; break;
        case 7: src = to_; K = 128; N = 128; off = 311296; break;
        default:src = gw;  K = 256; N = 128; off = 327680; break;
    }
    if (e >= K * N) return;
    const int nsh = (N == 256) ? 8 : 7;
    const int k = e >> nsh, n = e & (N - 1);
    float v = isF32 ? ((const float*)src)[e] : (float)((const bf16*)src)[e];
    dst[off + n * K + k] = (bf16)v;
}

// ---------------- BN batch-stats: per-channel sum & sumsq ----------------
__global__ __launch_bounds__(256) void bn_stats(
    const bf16* __restrict__ gi, float* __restrict__ stats)
{
    __shared__ float ssum[256], ssq[256];
    const size_t base = (size_t)blockIdx.x * 16384;   // 621*16384 == MTOT*128
    const int tid = threadIdx.x;
    float s = 0.f, sq = 0.f;
    #pragma unroll 4
    for (int i = 0; i < 64; ++i) {
        float v = (float)gi[base + (size_t)i * 256 + tid];
        s += v; sq += v * v;
    }
    ssum[tid] = s; ssq[tid] = sq;
    __syncthreads();
    if (tid < 128) {
        atomicAdd(&stats[tid], ssum[tid] + ssum[tid + 128]);
        atomicAdd(&stats[128 + tid], ssq[tid] + ssq[tid + 128]);
    }
}

// ---------------- final: z = sigmoid(BN(gi)); out = z*space + (1-z)*temp ----------------
__global__ __launch_bounds__(256) void bn_final(
    const bf16* __restrict__ gi, const bf16* __restrict__ sp, const bf16* __restrict__ tp,
    const void* __restrict__ gammav, const void* __restrict__ betav,
    const float* __restrict__ stats, void* __restrict__ outv,
    const int* __restrict__ dtf)
{
    const int isF32 = *dtf;
    const int idx = blockIdx.x * 256 + threadIdx.x;
    const int c = idx & 127;
    const float invM = 1.f / (float)MTOT;
    float mean = stats[c] * invM;
    float var  = stats[128 + c] * invM - mean * mean;
    float gam = isF32 ? ((const float*)gammav)[c] : (float)((const bf16*)gammav)[c];
    float bet = isF32 ? ((const float*)betav)[c]  : (float)((const bf16*)betav)[c];
    float g = (float)gi[idx];
    float zn = (g - mean) * rsqrtf(var + 1e-5f) * gam + bet;
    float z = 1.f / (1.f + __expf(-zn));
    float s = (float)sp[idx], t = (float)tp[idx];
    float r = z * s + (1.f - z) * t;
    if (isF32) ((float*)outv)[idx] = r;
    else       ((bf16*)outv)[idx] = (bf16)r;
}

static inline void launch_gemm(const void* A0, const void* A1, const bf16* Bt,
                               const void* bias, bf16* C, int Nout, int Ktot,
                               int relu, int aExt, int boff, const int* dtf, hipStream_t s)
{
    if (Nout >= 128)
        gemm_bt<128><<<dim3(621, Nout / 128), 256, 0, s>>>(A0, A1, Bt, bias, C, Nout, Ktot, relu, aExt, boff, dtf);
    else if (Nout == 64)
        gemm_bt<64><<<dim3(621, 1), 256, 0, s>>>(A0, A1, Bt, bias, C, Nout, Ktot, relu, aExt, boff, dtf);
    else
        gemm_bt<32><<<dim3(621, 1), 256, 0, s>>>(A0, A1, Bt, bias, C, Nout, Ktot, relu, aExt, boff, dtf);
}

extern "C" void kernel_launch(void* const* d_in, const int* in_sizes, int n_in,
                              void* d_out, int out_size, void* d_ws, size_t ws_size,
                              hipStream_t stream)
{
    const void* hidden = d_in[1];
    const void* tXin   = d_in[2];
    const void* sq_w = d_in[3];  const void* sq_b = d_in[4];
    const void* sk_w = d_in[5];  const void* sk_b = d_in[6];
    const void* sv_w = d_in[7];  const void* sv_b = d_in[8];
    const void* so_w = d_in[9];  const void* so_b = d_in[10];
    const void* tq_w = d_in[11]; const void* tq_b = d_in[12];
    const void* tk_w = d_in[13]; const void* tk_b = d_in[14];
    const void* tv_w = d_in[15]; const void* tv_b = d_in[16];
    const void* to_w = d_in[17]; const void* to_b = d_in[18];
    const void* gate_w = d_in[19]; const void* gate_b = d_in[20];
    const void* gamma  = d_in[21]; const void* beta   = d_in[22];

    char* ws = (char*)d_ws;
    float* stats = (float*)ws;                        // 1024 B
    int*  dtf    = (int*)(ws + 1024);
    bf16* wT     = (bf16*)(ws + 2048);
    bf16* spaceO = (bf16*)(ws + 722944);
    bf16* attnO  = (bf16*)(ws + 21071872);
    bf16* Qc     = (bf16*)(ws + 41420800);
    bf16* tempO  = attnO;                             // temporal out-proj in place

    const int CH = (ws_size >= 144000000ull) ? 8 : (ws_size >= 93000000ull ? 4 : 2);
    const int qs = CH * 32, vs = CH * 16, nchunk = 8 / CH;
    bf16* Kc = Qc + (size_t)MTOT * qs;
    bf16* Vc = Kc + (size_t)MTOT * qs;
    bf16* gi = Qc;

    bf16* sqT = wT;            bf16* skT = wT + 65536;
    bf16* svT = wT + 131072;   bf16* soT = wT + 147456;
    bf16* tqT = wT + 163840;   bf16* tkT = wT + 229376;
    bf16* tvT = wT + 294912;   bf16* toT = wT + 311296;
    bf16* gwT = wT + 327680;

    hipMemsetAsync(stats, 0, 1024, stream);
    detect_dtype<<<1, 256, 0, stream>>>(hidden, dtf);
    prep_weights<<<dim3(256, 9), 256, 0, stream>>>(sq_w, sk_w, sv_w, so_w,
                                                   tq_w, tk_w, tv_w, to_w, gate_w, wT, dtf);

    for (int br = 0; br < 2; ++br) {
        const bf16* qT = br ? tqT : sqT;  const void* qb = br ? tq_b : sq_b;
        const bf16* kT = br ? tkT : skT;  const void* kb = br ? tk_b : sk_b;
        const bf16* vT = br ? tvT : svT;  const void* vb = br ? tv_b : sv_b;
        const bf16* oT = br ? toT : soT;  const void* ob = br ? to_b : so_b;
        bf16* bro = br ? tempO : spaceO;

        for (int g = 0; g < nchunk; ++g) {
            launch_gemm(hidden, tXin, qT + (size_t)g * qs * 256, qb, Qc, qs, 256, 1, 1, g * qs, dtf, stream);
            launch_gemm(hidden, tXin, kT + (size_t)g * qs * 256, kb, Kc, qs, 256, 1, 1, g * qs, dtf, stream);
            launch_gemm(hidden, nullptr, vT + (size_t)g * vs * 128, vb, Vc, vs, 128, 1, 1, g * vs, dtf, stream);
            if (br == 0)
                attn_spatial_mfma<<<dim3(CH, TDIM, 16), 256, 0, stream>>>(Qc, Kc, Vc, attnO, qs, vs, g * CH);
            else
                attn_temporal<<<dim3(16 * NDIM), 256, 0, stream>>>(Qc, Kc, Vc, attnO, CH, g * CH);
        }
        launch_gemm(attnO, nullptr, oT, ob, bro, 128, 128, 1, 0, 0, dtf, stream);
    }

    launch_gemm(spaceO, tempO, gwT, gate_b, gi, 128, 256, 0, 0, 0, dtf, stream);
    bn_stats<<<dim3(621), 256, 0, stream>>>(gi, stats);
    bn_final<<<dim3(39744), 256, 0, stream>>>(gi, spaceO, tempO, gamma, beta, stats, d_out, dtf);
}

// Round 5
// 572.582 us; speedup vs baseline: 1.4191x; 1.1619x over previous
//
#include <hip/hip_runtime.h>
#include <hip/hip_bf16.h>

typedef __bf16 bf16;
typedef __bf16 bf16x8 __attribute__((ext_vector_type(8)));
typedef float f32x4 __attribute__((ext_vector_type(4)));

#define MTOT 79488   // 16*207*24
#define NDIM 207
#define TDIM 24

// ---------------- dtype detector: external tensors fp32 or bf16? ----------------
__global__ void detect_dtype(const void* __restrict__ hidden, int* __restrict__ flag)
{
    __shared__ int cnt;
    if (threadIdx.x == 0) cnt = 0;
    __syncthreads();
    const bf16* h = (const bf16*)hidden;
    int local = 0;
    for (int i = threadIdx.x; i < 4096; i += 256) {
        float v = (float)h[i];
        if (!(fabsf(v) < 1e6f)) local++;   // catches NaN/Inf too
    }
    atomicAdd(&cnt, local);
    __syncthreads();
    if (threadIdx.x == 0) *flag = (cnt > 8) ? 1 : 0;   // 1 => external data is fp32
}

__device__ inline float ld_ext(const void* p, int idx, int isF32)
{
    return isF32 ? ((const float*)p)[idx] : (float)((const bf16*)p)[idx];
}

// ---------------- weight prep: build concatenated transposed weights + bf16 biases ----
// wdst layout (elems): [0)      sW  [640n x 256k]  (q|k|v-zero-padded)
//                      [163840) tW  [640 x 256]
//                      [327680) soT [128 x 128]
//                      [344064) toT [128 x 128]
//                      [360448) gwT [128 x 256]   (end 393216)
// bdst: sB[640] | tB[640] | soB[128] | toB[128] | gB[128]  (1664)
__global__ __launch_bounds__(256) void prep_weights(
    const void* __restrict__ sq, const void* __restrict__ sk, const void* __restrict__ sv,
    const void* __restrict__ so, const void* __restrict__ tq, const void* __restrict__ tk,
    const void* __restrict__ tv, const void* __restrict__ to_, const void* __restrict__ gw,
    const void* __restrict__ sqb, const void* __restrict__ skb, const void* __restrict__ svb,
    const void* __restrict__ sob, const void* __restrict__ tqb, const void* __restrict__ tkb,
    const void* __restrict__ tvb, const void* __restrict__ tob, const void* __restrict__ gb,
    bf16* __restrict__ wdst, bf16* __restrict__ bdst, const int* __restrict__ dtf)
{
    const int isF32 = *dtf;
    if (blockIdx.x == 1536) {   // biases
        for (int j = threadIdx.x; j < 1664; j += 256) {
            const void* src; int i2;
            if      (j < 256)  { src = sqb; i2 = j; }
            else if (j < 512)  { src = skb; i2 = j - 256; }
            else if (j < 640)  { src = svb; i2 = j - 512; }
            else if (j < 896)  { src = tqb; i2 = j - 640; }
            else if (j < 1152) { src = tkb; i2 = j - 896; }
            else if (j < 1280) { src = tvb; i2 = j - 1152; }
            else if (j < 1408) { src = sob; i2 = j - 1280; }
            else if (j < 1536) { src = tob; i2 = j - 1408; }
            else               { src = gb;  i2 = j - 1536; }
            bdst[j] = (bf16)ld_ext(src, i2, isF32);
        }
        return;
    }
    const int e = blockIdx.x * 256 + threadIdx.x;
    float v;
    if (e < 327680) {
        int br = (e >= 163840);
        int e2 = e - br * 163840;
        int n = e2 >> 8, k = e2 & 255;
        const void* qw = br ? tq : sq;
        const void* kw = br ? tk : sk;
        const void* vw = br ? tv : sv;
        if      (n < 256) v = ld_ext(qw, k * 256 + n, isF32);
        else if (n < 512) v = ld_ext(kw, k * 256 + (n - 256), isF32);
        else              v = (k < 128) ? ld_ext(vw, k * 128 + (n - 512), isF32) : 0.f;
    } else if (e < 360448) {
        int br = (e >= 344064);
        int e2 = e - 327680 - br * 16384;
        int n = e2 >> 7, k = e2 & 127;
        v = ld_ext(br ? to_ : so, k * 128 + n, isF32);
    } else {
        int e2 = e - 360448;
        int n = e2 >> 8, k = e2 & 255;
        v = ld_ext(gw, k * 128 + n, isF32);
    }
    wdst[e] = (bf16)v;
}

// ---------------- GEMM: C[M,Nout] = act(A · Bt^T + bias) ----------------
// A logical [M,Ktot]: cols 0..127 from A0, 128..255 from A1 (row stride 128).
// aExt: A0/A1 are external (dtype per flag). Bt bf16 [>=Nout rows, Ktot]. bias bf16.
__global__ __launch_bounds__(256) void gemm_bt(
    const void* __restrict__ A0v, const void* __restrict__ A1v,
    const bf16* __restrict__ Bt, const bf16* __restrict__ bias,
    bf16* __restrict__ C, int Nout, int Ktot, int doRelu, int aExt,
    const int* __restrict__ dtf)
{
    const int isF32 = *dtf;
    const int aF32  = aExt & isF32;
    __shared__ bf16 As[128 * 72];
    __shared__ bf16 Bs[128 * 72];
    const int tid  = threadIdx.x;
    const int wid  = tid >> 6, lane = tid & 63;
    const int wm   = (wid >> 1) * 64, wn = (wid & 1) * 64;
    const int quad = lane >> 4, l16 = lane & 15;
    const int m0   = blockIdx.x * 128, n0 = blockIdx.y * 128;
    const int lrow = tid >> 3;
    const int lcol = (tid & 7) * 8;

    f32x4 acc[4][4] = {};

    for (int k0 = 0; k0 < Ktot; k0 += 64) {
        const void* Ap = (k0 < 128) ? A0v : A1v;
        const int koff = (k0 < 128) ? k0 : k0 - 128;
        #pragma unroll
        for (int p = 0; p < 4; ++p) {
            int r = lrow + p * 32;
            bf16x8 av;
            if (aF32) {
                const float* Af = (const float*)Ap;
                f32x4 lo = *(const f32x4*)(Af + (size_t)(m0 + r) * 128 + koff + lcol);
                f32x4 hi = *(const f32x4*)(Af + (size_t)(m0 + r) * 128 + koff + lcol + 4);
                av[0]=(bf16)lo[0]; av[1]=(bf16)lo[1]; av[2]=(bf16)lo[2]; av[3]=(bf16)lo[3];
                av[4]=(bf16)hi[0]; av[5]=(bf16)hi[1]; av[6]=(bf16)hi[2]; av[7]=(bf16)hi[3];
            } else {
                av = *(const bf16x8*)((const bf16*)Ap + (size_t)(m0 + r) * 128 + koff + lcol);
            }
            *(bf16x8*)&As[r * 72 + lcol] = av;
        }
        #pragma unroll
        for (int p = 0; p < 4; ++p) {
            int r = lrow + p * 32;
            *(bf16x8*)&Bs[r * 72 + lcol] =
                *(const bf16x8*)(Bt + (size_t)(n0 + r) * Ktot + k0 + lcol);
        }
        __syncthreads();
        #pragma unroll
        for (int kk = 0; kk < 64; kk += 32) {
            bf16x8 af[4], bfr[4];
            #pragma unroll
            for (int i = 0; i < 4; ++i)
                af[i] = *(const bf16x8*)&As[(wm + i * 16 + l16) * 72 + kk + quad * 8];
            #pragma unroll
            for (int j = 0; j < 4; ++j)
                bfr[j] = *(const bf16x8*)&Bs[(wn + j * 16 + l16) * 72 + kk + quad * 8];
            #pragma unroll
            for (int i = 0; i < 4; ++i)
                #pragma unroll
                for (int j = 0; j < 4; ++j)
                    acc[i][j] = __builtin_amdgcn_mfma_f32_16x16x32_bf16(
                        af[i], bfr[j], acc[i][j], 0, 0, 0);
        }
        __syncthreads();
    }
    #pragma unroll
    for (int j = 0; j < 4; ++j) {
        int col = n0 + wn + j * 16 + l16;
        float bv = (float)bias[col];
        #pragma unroll
        for (int i = 0; i < 4; ++i) {
            int rbase = m0 + wm + i * 16 + quad * 4;
            #pragma unroll
            for (int r = 0; r < 4; ++r) {
                float v = acc[i][j][r] + bv;
                if (doRelu) v = fmaxf(v, 0.f);
                C[(size_t)(rbase + r) * Nout + col] = (bf16)v;
            }
        }
    }
}

// ---------------- spatial attention, MFMA full-score ----------------
// QKV [M,640]: Q cols 0..255, K 256..511, V 512..639. Block per (hh,t,b).
// All 224 scores held in 14 C-fragments; single max/sum reduction per q-row.
__global__ __launch_bounds__(256) void attn_spatial_mfma(
    const bf16* __restrict__ QKV, bf16* __restrict__ O)
{
    const int hh = blockIdx.x, t = blockIdx.y, b = blockIdx.z;
    __shared__ bf16 Ks[224 * 40];      // K head-slice, stride 40 halves
    __shared__ bf16 Vt[16 * 232];      // V transposed
    __shared__ bf16 Pl[4][16 * 40];    // wave-private P chunk tiles
    const int tid = threadIdx.x;
    const int wave = tid >> 6, lane = tid & 63;
    const int quad = lane >> 4, l16 = lane & 15;
    const int STR = 640;

    for (int idx = tid; idx < 224 * 4; idx += 256) {
        int n = idx >> 2, seg = (idx & 3) * 8;
        bf16x8 v8 = {};
        if (n < NDIM)
            v8 = *(const bf16x8*)(QKV + ((size_t)(b * NDIM + n) * TDIM + t) * STR
                                  + 256 + hh * 32 + seg);
        *(bf16x8*)&Ks[n * 40 + seg] = v8;
    }
    for (int idx = tid; idx < 224 * 16; idx += 256) {
        int s = idx >> 4, d = idx & 15;
        bf16 v = (bf16)0.f;
        if (s < NDIM)
            v = QKV[((size_t)(b * NDIM + s) * TDIM + t) * STR + 512 + hh * 16 + d];
        Vt[d * 232 + s] = v;
    }
    __syncthreads();

    const float scale = 0.17677669529663687f;   // 1/sqrt(32)

    for (int qt = wave; qt < 13; qt += 4) {
        const int q0 = qt * 16;
        int qrow = q0 + l16; if (qrow >= NDIM) qrow = NDIM - 1;
        bf16x8 qfrag = *(const bf16x8*)(QKV + ((size_t)(b * NDIM + qrow) * TDIM + t) * STR
                                        + hh * 32 + quad * 8);
        // scores: 14 MFMAs, all 224 s in registers
        f32x4 s[14];
        #pragma unroll
        for (int c = 0; c < 14; ++c) {
            bf16x8 kf = *(const bf16x8*)&Ks[(c * 16 + l16) * 40 + quad * 8];
            f32x4 z = {};
            s[c] = __builtin_amdgcn_mfma_f32_16x16x32_bf16(qfrag, kf, z, 0, 0, 0);
        }
        // softmax per q-row (row = quad*4+r), batched reductions
        float l[4];
        #pragma unroll
        for (int r = 0; r < 4; ++r) {
            float mx = -1e30f;
            #pragma unroll
            for (int c = 0; c < 14; ++c) {
                int si = c * 16 + l16;
                float x = (si < NDIM) ? s[c][r] : -1e30f;
                mx = fmaxf(mx, x);
            }
            mx = fmaxf(mx, __shfl_xor(mx, 1));
            mx = fmaxf(mx, __shfl_xor(mx, 2));
            mx = fmaxf(mx, __shfl_xor(mx, 4));
            mx = fmaxf(mx, __shfl_xor(mx, 8));
            float sum = 0.f;
            #pragma unroll
            for (int c = 0; c < 14; ++c) {
                int si = c * 16 + l16;
                float p = (si < NDIM) ? __expf((s[c][r] - mx) * scale) : 0.f;
                s[c][r] = p;
                sum += p;
            }
            sum += __shfl_xor(sum, 1);
            sum += __shfl_xor(sum, 2);
            sum += __shfl_xor(sum, 4);
            sum += __shfl_xor(sum, 8);
            l[r] = sum;
        }
        // PV: 7 chunk MFMAs via wave-private LDS P-tile (C-layout -> A-layout)
        f32x4 oacc = {};
        #pragma unroll
        for (int sc = 0; sc < 7; ++sc) {
            #pragma unroll
            for (int r = 0; r < 4; ++r) {
                Pl[wave][(quad * 4 + r) * 40 + l16]      = (bf16)s[2 * sc][r];
                Pl[wave][(quad * 4 + r) * 40 + 16 + l16] = (bf16)s[2 * sc + 1][r];
            }
            bf16x8 pf = *(const bf16x8*)&Pl[wave][l16 * 40 + quad * 8];
            bf16x8 vf = *(const bf16x8*)&Vt[l16 * 232 + sc * 32 + quad * 8];
            oacc = __builtin_amdgcn_mfma_f32_16x16x32_bf16(pf, vf, oacc, 0, 0, 0);
        }
        #pragma unroll
        for (int r = 0; r < 4; ++r) {
            int row = q0 + quad * 4 + r;
            if (row < NDIM)
                O[((size_t)(b * NDIM + row) * TDIM + t) * 128 + hh * 16 + l16]
                    = (bf16)(oacc[r] / l[r]);
        }
    }
}

// ---------------- temporal attention: block per (b,n), causal over T=24 ----------------
__global__ __launch_bounds__(256) void attn_temporal(
    const bf16* __restrict__ QKV, bf16* __restrict__ O)
{
    const size_t m0 = (size_t)blockIdx.x * TDIM;
    __shared__ float Ks[TDIM][256];
    __shared__ float Vs[TDIM][128];
    const int tid = threadIdx.x;
    const int STR = 640;

    for (int idx = tid; idx < TDIM * 32; idx += 256) {
        int row = idx >> 5, c8 = (idx & 31) * 8;
        bf16x8 v = *(const bf16x8*)(QKV + (m0 + row) * STR + 256 + c8);
        #pragma unroll
        for (int j = 0; j < 8; ++j) Ks[row][c8 + j] = (float)v[j];
    }
    for (int idx = tid; idx < TDIM * 16; idx += 256) {
        int row = idx >> 4, c8 = (idx & 15) * 8;
        bf16x8 v = *(const bf16x8*)(QKV + (m0 + row) * STR + 512 + c8);
        #pragma unroll
        for (int j = 0; j < 8; ++j) Vs[row][c8 + j] = (float)v[j];
    }
    __syncthreads();

    if (tid < 8 * TDIM) {
        const int h = tid / TDIM, q = tid % TDIM;
        float qv[32];
        const bf16x8* qp = (const bf16x8*)(QKV + (m0 + q) * STR + h * 32);
        #pragma unroll
        for (int cc = 0; cc < 4; ++cc) {
            bf16x8 v = qp[cc];
            #pragma unroll
            for (int jj = 0; jj < 8; ++jj) qv[cc * 8 + jj] = (float)v[jj];
        }
        const float scale = 0.17677669529663687f;
        float mx = -1e29f, l = 0.f, acc[16] = {};
        for (int s = 0; s <= q; ++s) {   // strict-upper-tri mask => attend s<=q
            float x = 0.f;
            #pragma unroll
            for (int c = 0; c < 32; ++c) x += qv[c] * Ks[s][h * 32 + c];
            x *= scale;
            float mn = fmaxf(mx, x);
            float corr = __expf(mx - mn);
            float p = __expf(x - mn);
            l = l * corr + p;
            #pragma unroll
            for (int d = 0; d < 16; ++d) acc[d] = acc[d] * corr + p * Vs[s][h * 16 + d];
            mx = mn;
        }
        float inv = 1.f / l;
        #pragma unroll
        for (int d = 0; d < 16; ++d)
            O[(m0 + q) * 128 + h * 16 + d] = (bf16)(acc[d] * inv);
    }
}

// ---------------- BN batch-stats ----------------
__global__ __launch_bounds__(256) void bn_stats(
    const bf16* __restrict__ gi, float* __restrict__ stats)
{
    __shared__ float ssum[256], ssq[256];
    const size_t base = (size_t)blockIdx.x * 16384;
    const int tid = threadIdx.x;
    float s = 0.f, sq = 0.f;
    #pragma unroll 4
    for (int i = 0; i < 64; ++i) {
        float v = (float)gi[base + (size_t)i * 256 + tid];
        s += v; sq += v * v;
    }
    ssum[tid] = s; ssq[tid] = sq;
    __syncthreads();
    if (tid < 128) {
        atomicAdd(&stats[tid], ssum[tid] + ssum[tid + 128]);
        atomicAdd(&stats[128 + tid], ssq[tid] + ssq[tid + 128]);
    }
}

// ---------------- final: z = sigmoid(BN(gi)); out = z*space + (1-z)*temp ----------------
__global__ __launch_bounds__(256) void bn_final(
    const bf16* __restrict__ gi, const bf16* __restrict__ sp, const bf16* __restrict__ tp,
    const void* __restrict__ gammav, const void* __restrict__ betav,
    const float* __restrict__ stats, void* __restrict__ outv,
    const int* __restrict__ dtf)
{
    const int isF32 = *dtf;
    const int idx = blockIdx.x * 256 + threadIdx.x;
    const int c = idx & 127;
    const float invM = 1.f / (float)MTOT;
    float mean = stats[c] * invM;
    float var  = stats[128 + c] * invM - mean * mean;
    float gam = ld_ext(gammav, c, isF32);
    float bet = ld_ext(betav, c, isF32);
    float g = (float)gi[idx];
    float zn = (g - mean) * rsqrtf(var + 1e-5f) * gam + bet;
    float z = 1.f / (1.f + __expf(-zn));
    float s = (float)sp[idx], t = (float)tp[idx];
    float r = z * s + (1.f - z) * t;
    if (isF32) ((float*)outv)[idx] = r;
    else       ((bf16*)outv)[idx] = (bf16)r;
}

extern "C" void kernel_launch(void* const* d_in, const int* in_sizes, int n_in,
                              void* d_out, int out_size, void* d_ws, size_t ws_size,
                              hipStream_t stream)
{
    const void* hidden = d_in[1];
    const void* tXin   = d_in[2];
    const void* sq_w = d_in[3];  const void* sq_b = d_in[4];
    const void* sk_w = d_in[5];  const void* sk_b = d_in[6];
    const void* sv_w = d_in[7];  const void* sv_b = d_in[8];
    const void* so_w = d_in[9];  const void* so_b = d_in[10];
    const void* tq_w = d_in[11]; const void* tq_b = d_in[12];
    const void* tk_w = d_in[13]; const void* tk_b = d_in[14];
    const void* tv_w = d_in[15]; const void* tv_b = d_in[16];
    const void* to_w = d_in[17]; const void* to_b = d_in[18];
    const void* gate_w = d_in[19]; const void* gate_b = d_in[20];
    const void* gamma  = d_in[21]; const void* beta   = d_in[22];

    // ---- workspace layout ----
    char* ws = (char*)d_ws;
    float* stats = (float*)ws;                        // 1 KB
    int*  dtf    = (int*)(ws + 1024);
    bf16* bB     = (bf16*)(ws + 2048);                // 1664 bf16 biases
    bf16* wT     = (bf16*)(ws + 8192);                // 393216 bf16 weights
    bf16* spaceO = (bf16*)(ws + 794624);              // M*128
    bf16* attnO  = (bf16*)(ws + 21143552);            // M*128 (tempO in-place)
    bf16* QKV    = (bf16*)(ws + 41492480);            // M*640 (ends 143,237,120)
    bf16* tempO  = attnO;
    bf16* gi     = QKV;                               // alias; QKV dead by gate time

    bf16* sW  = wT;            bf16* tW  = wT + 163840;
    bf16* soT = wT + 327680;   bf16* toT = wT + 344064;
    bf16* gwT = wT + 360448;

    hipMemsetAsync(stats, 0, 1024, stream);
    detect_dtype<<<1, 256, 0, stream>>>(hidden, dtf);
    prep_weights<<<dim3(1537), 256, 0, stream>>>(
        sq_w, sk_w, sv_w, so_w, tq_w, tk_w, tv_w, to_w, gate_w,
        sq_b, sk_b, sv_b, so_b, tq_b, tk_b, tv_b, to_b, gate_b,
        wT, bB, dtf);

    // ---- spatial branch ----
    gemm_bt<<<dim3(621, 5), 256, 0, stream>>>(hidden, tXin, sW, bB, QKV, 640, 256, 1, 1, dtf);
    attn_spatial_mfma<<<dim3(8, TDIM, 16), 256, 0, stream>>>(QKV, attnO);
    gemm_bt<<<dim3(621, 1), 256, 0, stream>>>(attnO, nullptr, soT, bB + 1280, spaceO, 128, 128, 1, 0, dtf);

    // ---- temporal branch ----
    gemm_bt<<<dim3(621, 5), 256, 0, stream>>>(hidden, tXin, tW, bB + 640, QKV, 640, 256, 1, 1, dtf);
    attn_temporal<<<dim3(16 * NDIM), 256, 0, stream>>>(QKV, attnO);
    gemm_bt<<<dim3(621, 1), 256, 0, stream>>>(attnO, nullptr, toT, bB + 1408, tempO, 128, 128, 1, 0, dtf);

    // ---- gate + BN + blend ----
    gemm_bt<<<dim3(621, 1), 256, 0, stream>>>(spaceO, tempO, gwT, bB + 1536, gi, 128, 256, 0, 0, dtf);
    bn_stats<<<dim3(621), 256, 0, stream>>>(gi, stats);
    bn_final<<<dim3(39744), 256, 0, stream>>>(gi, spaceO, tempO, gamma, beta, stats, d_out, dtf);
}

// Round 6
// 544.244 us; speedup vs baseline: 1.4930x; 1.0521x over previous
//
#include <hip/hip_runtime.h>
#include <hip/hip_bf16.h>

typedef __bf16 bf16;
typedef __bf16 bf16x8 __attribute__((ext_vector_type(8)));
typedef float f32x4 __attribute__((ext_vector_type(4)));

#define MTOT 79488   // 16*207*24
#define NDIM 207
#define TDIM 24

// ---------------- dtype detector: external tensors fp32 or bf16? ----------------
__global__ void detect_dtype(const void* __restrict__ hidden, int* __restrict__ flag)
{
    __shared__ int cnt;
    if (threadIdx.x == 0) cnt = 0;
    __syncthreads();
    const bf16* h = (const bf16*)hidden;
    int local = 0;
    for (int i = threadIdx.x; i < 4096; i += 256) {
        float v = (float)h[i];
        if (!(fabsf(v) < 1e6f)) local++;   // catches NaN/Inf too
    }
    atomicAdd(&cnt, local);
    __syncthreads();
    if (threadIdx.x == 0) *flag = (cnt > 8) ? 1 : 0;   // 1 => external data is fp32
}

__device__ inline float ld_ext(const void* p, int idx, int isF32)
{
    return isF32 ? ((const float*)p)[idx] : (float)((const bf16*)p)[idx];
}

// ---------------- input convert: hidden/tXin -> bf16 [M,128] each ----------------
__global__ __launch_bounds__(256) void cvt_inputs(
    const void* __restrict__ hidden, const void* __restrict__ tXin,
    bf16* __restrict__ hb, bf16* __restrict__ tb, const int* __restrict__ dtf)
{
    const int isF32 = *dtf;
    const void* src = blockIdx.y ? tXin : hidden;
    bf16* dst = blockIdx.y ? tb : hb;
    const size_t e8 = ((size_t)blockIdx.x * 256 + threadIdx.x) * 8;   // covers M*128
    bf16x8 v;
    if (isF32) {
        f32x4 lo = *(const f32x4*)((const float*)src + e8);
        f32x4 hi = *(const f32x4*)((const float*)src + e8 + 4);
        v[0]=(bf16)lo[0]; v[1]=(bf16)lo[1]; v[2]=(bf16)lo[2]; v[3]=(bf16)lo[3];
        v[4]=(bf16)hi[0]; v[5]=(bf16)hi[1]; v[6]=(bf16)hi[2]; v[7]=(bf16)hi[3];
    } else {
        v = *(const bf16x8*)((const bf16*)src + e8);
    }
    *(bf16x8*)(dst + e8) = v;
}

// ---------------- weight prep: concatenated transposed weights + bf16 biases ----
// wdst: [0) sW[640x256] | [163840) tW[640x256] | [327680) soT[128x128]
//       [344064) toT[128x128] | [360448) gwT[128x256]  (end 393216)
// bdst: sB[640] | tB[640] | soB[128] | toB[128] | gB[128]
__global__ __launch_bounds__(256) void prep_weights(
    const void* __restrict__ sq, const void* __restrict__ sk, const void* __restrict__ sv,
    const void* __restrict__ so, const void* __restrict__ tq, const void* __restrict__ tk,
    const void* __restrict__ tv, const void* __restrict__ to_, const void* __restrict__ gw,
    const void* __restrict__ sqb, const void* __restrict__ skb, const void* __restrict__ svb,
    const void* __restrict__ sob, const void* __restrict__ tqb, const void* __restrict__ tkb,
    const void* __restrict__ tvb, const void* __restrict__ tob, const void* __restrict__ gb,
    bf16* __restrict__ wdst, bf16* __restrict__ bdst, const int* __restrict__ dtf)
{
    const int isF32 = *dtf;
    if (blockIdx.x == 1536) {   // biases
        for (int j = threadIdx.x; j < 1664; j += 256) {
            const void* src; int i2;
            if      (j < 256)  { src = sqb; i2 = j; }
            else if (j < 512)  { src = skb; i2 = j - 256; }
            else if (j < 640)  { src = svb; i2 = j - 512; }
            else if (j < 896)  { src = tqb; i2 = j - 640; }
            else if (j < 1152) { src = tkb; i2 = j - 896; }
            else if (j < 1280) { src = tvb; i2 = j - 1152; }
            else if (j < 1408) { src = sob; i2 = j - 1280; }
            else if (j < 1536) { src = tob; i2 = j - 1408; }
            else               { src = gb;  i2 = j - 1536; }
            bdst[j] = (bf16)ld_ext(src, i2, isF32);
        }
        return;
    }
    const int e = blockIdx.x * 256 + threadIdx.x;
    float v;
    if (e < 327680) {
        int br = (e >= 163840);
        int e2 = e - br * 163840;
        int n = e2 >> 8, k = e2 & 255;
        const void* qw = br ? tq : sq;
        const void* kw = br ? tk : sk;
        const void* vw = br ? tv : sv;
        if      (n < 256) v = ld_ext(qw, k * 256 + n, isF32);
        else if (n < 512) v = ld_ext(kw, k * 256 + (n - 256), isF32);
        else              v = (k < 128) ? ld_ext(vw, k * 128 + (n - 512), isF32) : 0.f;
    } else if (e < 360448) {
        int br = (e >= 344064);
        int e2 = e - 327680 - br * 16384;
        int n = e2 >> 7, k = e2 & 127;
        v = ld_ext(br ? to_ : so, k * 128 + n, isF32);
    } else {
        int e2 = e - 360448;
        int n = e2 >> 8, k = e2 & 255;
        v = ld_ext(gw, k * 128 + n, isF32);
    }
    wdst[e] = (bf16)v;
}

// ---------------- GEMM: C[M,Nout] = act(A · Bt^T + bias) ----------------
// A logical [M,Ktot]: cols 0..127 from A0, 128..255 from A1 (row stride 128).
// aExt=1: A0/A1 external, dtype per dtf. Otherwise internal bf16.
__global__ __launch_bounds__(256) void gemm_bt(
    const void* __restrict__ A0v, const void* __restrict__ A1v,
    const bf16* __restrict__ Bt, const bf16* __restrict__ bias,
    bf16* __restrict__ C, int Nout, int Ktot, int doRelu, int aExt,
    const int* __restrict__ dtf)
{
    const int aF32 = aExt & *dtf;
    __shared__ bf16 As[128 * 72];
    __shared__ bf16 Bs[128 * 72];
    const int tid  = threadIdx.x;
    const int wid  = tid >> 6, lane = tid & 63;
    const int wm   = (wid >> 1) * 64, wn = (wid & 1) * 64;
    const int quad = lane >> 4, l16 = lane & 15;
    const int m0   = blockIdx.x * 128, n0 = blockIdx.y * 128;
    const int lrow = tid >> 3;
    const int lcol = (tid & 7) * 8;

    f32x4 acc[4][4] = {};

    for (int k0 = 0; k0 < Ktot; k0 += 64) {
        const void* Ap = (k0 < 128) ? A0v : A1v;
        const int koff = (k0 < 128) ? k0 : k0 - 128;
        #pragma unroll
        for (int p = 0; p < 4; ++p) {
            int r = lrow + p * 32;
            bf16x8 av;
            if (aF32) {
                const float* Af = (const float*)Ap;
                f32x4 lo = *(const f32x4*)(Af + (size_t)(m0 + r) * 128 + koff + lcol);
                f32x4 hi = *(const f32x4*)(Af + (size_t)(m0 + r) * 128 + koff + lcol + 4);
                av[0]=(bf16)lo[0]; av[1]=(bf16)lo[1]; av[2]=(bf16)lo[2]; av[3]=(bf16)lo[3];
                av[4]=(bf16)hi[0]; av[5]=(bf16)hi[1]; av[6]=(bf16)hi[2]; av[7]=(bf16)hi[3];
            } else {
                av = *(const bf16x8*)((const bf16*)Ap + (size_t)(m0 + r) * 128 + koff + lcol);
            }
            *(bf16x8*)&As[r * 72 + lcol] = av;
        }
        #pragma unroll
        for (int p = 0; p < 4; ++p) {
            int r = lrow + p * 32;
            *(bf16x8*)&Bs[r * 72 + lcol] =
                *(const bf16x8*)(Bt + (size_t)(n0 + r) * Ktot + k0 + lcol);
        }
        __syncthreads();
        #pragma unroll
        for (int kk = 0; kk < 64; kk += 32) {
            bf16x8 af[4], bfr[4];
            #pragma unroll
            for (int i = 0; i < 4; ++i)
                af[i] = *(const bf16x8*)&As[(wm + i * 16 + l16) * 72 + kk + quad * 8];
            #pragma unroll
            for (int j = 0; j < 4; ++j)
                bfr[j] = *(const bf16x8*)&Bs[(wn + j * 16 + l16) * 72 + kk + quad * 8];
            #pragma unroll
            for (int i = 0; i < 4; ++i)
                #pragma unroll
                for (int j = 0; j < 4; ++j)
                    acc[i][j] = __builtin_amdgcn_mfma_f32_16x16x32_bf16(
                        af[i], bfr[j], acc[i][j], 0, 0, 0);
        }
        __syncthreads();
    }
    #pragma unroll
    for (int j = 0; j < 4; ++j) {
        int col = n0 + wn + j * 16 + l16;
        float bv = (float)bias[col];
        #pragma unroll
        for (int i = 0; i < 4; ++i) {
            int rbase = m0 + wm + i * 16 + quad * 4;
            #pragma unroll
            for (int r = 0; r < 4; ++r) {
                float v = acc[i][j][r] + bv;
                if (doRelu) v = fmaxf(v, 0.f);
                C[(size_t)(rbase + r) * Nout + col] = (bf16)v;
            }
        }
    }
}

// ---------------- spatial attention, MFMA full-score ----------------
// QKV [M,640]: Q 0..255, K 256..511, V 512..639. Block per (hh,t,b).
__global__ __launch_bounds__(256) void attn_spatial_mfma(
    const bf16* __restrict__ QKV, bf16* __restrict__ O)
{
    const int hh = blockIdx.x, t = blockIdx.y, b = blockIdx.z;
    __shared__ bf16 Ks[224 * 40];
    __shared__ bf16 Vt[16 * 232];
    __shared__ bf16 Pl[4][16 * 40];
    const int tid = threadIdx.x;
    const int wave = tid >> 6, lane = tid & 63;
    const int quad = lane >> 4, l16 = lane & 15;
    const int STR = 640;

    for (int idx = tid; idx < 224 * 4; idx += 256) {
        int n = idx >> 2, seg = (idx & 3) * 8;
        bf16x8 v8 = {};
        if (n < NDIM)
            v8 = *(const bf16x8*)(QKV + ((size_t)(b * NDIM + n) * TDIM + t) * STR
                                  + 256 + hh * 32 + seg);
        *(bf16x8*)&Ks[n * 40 + seg] = v8;
    }
    for (int idx = tid; idx < 224 * 16; idx += 256) {
        int s = idx >> 4, d = idx & 15;
        bf16 v = (bf16)0.f;
        if (s < NDIM)
            v = QKV[((size_t)(b * NDIM + s) * TDIM + t) * STR + 512 + hh * 16 + d];
        Vt[d * 232 + s] = v;
    }
    __syncthreads();

    const float scale = 0.17677669529663687f;   // 1/sqrt(32)

    for (int qt = wave; qt < 13; qt += 4) {
        const int q0 = qt * 16;
        int qrow = q0 + l16; if (qrow >= NDIM) qrow = NDIM - 1;
        bf16x8 qfrag = *(const bf16x8*)(QKV + ((size_t)(b * NDIM + qrow) * TDIM + t) * STR
                                        + hh * 32 + quad * 8);
        f32x4 s[14];
        #pragma unroll
        for (int c = 0; c < 14; ++c) {
            bf16x8 kf = *(const bf16x8*)&Ks[(c * 16 + l16) * 40 + quad * 8];
            f32x4 z = {};
            s[c] = __builtin_amdgcn_mfma_f32_16x16x32_bf16(qfrag, kf, z, 0, 0, 0);
        }
        float l[4];
        #pragma unroll
        for (int r = 0; r < 4; ++r) {
            float mx = -1e30f;
            #pragma unroll
            for (int c = 0; c < 14; ++c) {
                int si = c * 16 + l16;
                float x = (si < NDIM) ? s[c][r] : -1e30f;
                mx = fmaxf(mx, x);
            }
            mx = fmaxf(mx, __shfl_xor(mx, 1));
            mx = fmaxf(mx, __shfl_xor(mx, 2));
            mx = fmaxf(mx, __shfl_xor(mx, 4));
            mx = fmaxf(mx, __shfl_xor(mx, 8));
            float sum = 0.f;
            #pragma unroll
            for (int c = 0; c < 14; ++c) {
                int si = c * 16 + l16;
                float p = (si < NDIM) ? __expf((s[c][r] - mx) * scale) : 0.f;
                s[c][r] = p;
                sum += p;
            }
            sum += __shfl_xor(sum, 1);
            sum += __shfl_xor(sum, 2);
            sum += __shfl_xor(sum, 4);
            sum += __shfl_xor(sum, 8);
            l[r] = sum;
        }
        f32x4 oacc = {};
        #pragma unroll
        for (int sc = 0; sc < 7; ++sc) {
            #pragma unroll
            for (int r = 0; r < 4; ++r) {
                Pl[wave][(quad * 4 + r) * 40 + l16]      = (bf16)s[2 * sc][r];
                Pl[wave][(quad * 4 + r) * 40 + 16 + l16] = (bf16)s[2 * sc + 1][r];
            }
            bf16x8 pf = *(const bf16x8*)&Pl[wave][l16 * 40 + quad * 8];
            bf16x8 vf = *(const bf16x8*)&Vt[l16 * 232 + sc * 32 + quad * 8];
            oacc = __builtin_amdgcn_mfma_f32_16x16x32_bf16(pf, vf, oacc, 0, 0, 0);
        }
        #pragma unroll
        for (int r = 0; r < 4; ++r) {
            int row = q0 + quad * 4 + r;
            if (row < NDIM)
                O[((size_t)(b * NDIM + row) * TDIM + t) * 128 + hh * 16 + l16]
                    = (bf16)(oacc[r] / l[r]);
        }
    }
}

// ---------------- temporal attention, MFMA, causal ----------------
// Block per (b,n). Wave w handles heads 2w, 2w+1; 2 q-tiles each (T=24 -> 16+8).
__global__ __launch_bounds__(256) void attn_temporal_mfma(
    const bf16* __restrict__ QKV, bf16* __restrict__ O)
{
    const size_t m0 = (size_t)blockIdx.x * TDIM;
    __shared__ bf16 Khs[8 * 32 * 40];   // [h][s(pad32)][c(pad40)]
    __shared__ bf16 Vts[8 * 16 * 40];   // [h][d][s(pad40)]
    __shared__ bf16 Pl[4][16 * 40];
    const int tid = threadIdx.x;
    const int wave = tid >> 6, lane = tid & 63;
    const int quad = lane >> 4, l16 = lane & 15;
    const int STR = 640;

    for (int idx = tid; idx < 32 * 32; idx += 256) {
        int row = idx >> 5, seg = idx & 31;
        int h = seg >> 2, j = (seg & 3) * 8;
        bf16x8 v8 = {};
        if (row < TDIM)
            v8 = *(const bf16x8*)(QKV + (m0 + row) * STR + 256 + h * 32 + j);
        *(bf16x8*)&Khs[h * 1280 + row * 40 + j] = v8;
    }
    for (int idx = tid; idx < 32 * 128; idx += 256) {
        int s = idx >> 7, c = idx & 127;
        int h = c >> 4, d = c & 15;
        bf16 v = (bf16)0.f;
        if (s < TDIM) v = QKV[(m0 + s) * STR + 512 + h * 16 + d];
        Vts[h * 640 + d * 40 + s] = v;
    }
    __syncthreads();

    const float scale = 0.17677669529663687f;

    #pragma unroll
    for (int hi = 0; hi < 2; ++hi) {
        const int h = wave * 2 + hi;
        #pragma unroll
        for (int qt = 0; qt < 2; ++qt) {
            int qrow = qt * 16 + l16; if (qrow >= TDIM) qrow = TDIM - 1;
            bf16x8 qfrag = *(const bf16x8*)(QKV + (m0 + qrow) * STR + h * 32 + quad * 8);
            bf16x8 kf0 = *(const bf16x8*)&Khs[h * 1280 + l16 * 40 + quad * 8];
            bf16x8 kf1 = *(const bf16x8*)&Khs[h * 1280 + (16 + l16) * 40 + quad * 8];
            f32x4 z = {};
            f32x4 s0 = __builtin_amdgcn_mfma_f32_16x16x32_bf16(qfrag, kf0, z, 0, 0, 0);
            f32x4 s1 = __builtin_amdgcn_mfma_f32_16x16x32_bf16(qfrag, kf1, z, 0, 0, 0);
            float l[4];
            #pragma unroll
            for (int r = 0; r < 4; ++r) {
                int q = qt * 16 + quad * 4 + r;
                float x0 = (l16 <= q) ? s0[r] : -1e30f;                       // causal: s<=q
                float x1 = (16 + l16 <= q && 16 + l16 < TDIM) ? s1[r] : -1e30f;
                float mx = fmaxf(x0, x1);
                mx = fmaxf(mx, __shfl_xor(mx, 1));
                mx = fmaxf(mx, __shfl_xor(mx, 2));
                mx = fmaxf(mx, __shfl_xor(mx, 4));
                mx = fmaxf(mx, __shfl_xor(mx, 8));
                float p0 = (x0 > -1e29f) ? __expf((x0 - mx) * scale) : 0.f;
                float p1 = (x1 > -1e29f) ? __expf((x1 - mx) * scale) : 0.f;
                float sum = p0 + p1;
                sum += __shfl_xor(sum, 1);
                sum += __shfl_xor(sum, 2);
                sum += __shfl_xor(sum, 4);
                sum += __shfl_xor(sum, 8);
                l[r] = sum;
                Pl[wave][(quad * 4 + r) * 40 + l16]      = (bf16)p0;
                Pl[wave][(quad * 4 + r) * 40 + 16 + l16] = (bf16)p1;
            }
            bf16x8 pf = *(const bf16x8*)&Pl[wave][l16 * 40 + quad * 8];
            bf16x8 vf = *(const bf16x8*)&Vts[h * 640 + l16 * 40 + quad * 8];
            f32x4 oacc = __builtin_amdgcn_mfma_f32_16x16x32_bf16(pf, vf, z, 0, 0, 0);
            #pragma unroll
            for (int r = 0; r < 4; ++r) {
                int row = qt * 16 + quad * 4 + r;
                if (row < TDIM)
                    O[(m0 + row) * 128 + h * 16 + l16] = (bf16)(oacc[r] / l[r]);
            }
        }
    }
}

// ---------------- BN batch-stats ----------------
__global__ __launch_bounds__(256) void bn_stats(
    const bf16* __restrict__ gi, float* __restrict__ stats)
{
    __shared__ float ssum[256], ssq[256];
    const size_t base = (size_t)blockIdx.x * 16384;
    const int tid = threadIdx.x;
    float s = 0.f, sq = 0.f;
    #pragma unroll 4
    for (int i = 0; i < 64; ++i) {
        float v = (float)gi[base + (size_t)i * 256 + tid];
        s += v; sq += v * v;
    }
    ssum[tid] = s; ssq[tid] = sq;
    __syncthreads();
    if (tid < 128) {
        atomicAdd(&stats[tid], ssum[tid] + ssum[tid + 128]);
        atomicAdd(&stats[128 + tid], ssq[tid] + ssq[tid + 128]);
    }
}

// ---------------- final: z = sigmoid(BN(gi)); out = z*space + (1-z)*temp ----------------
__global__ __launch_bounds__(256) void bn_final(
    const bf16* __restrict__ gi, const bf16* __restrict__ sp, const bf16* __restrict__ tp,
    const void* __restrict__ gammav, const void* __restrict__ betav,
    const float* __restrict__ stats, void* __restrict__ outv,
    const int* __restrict__ dtf)
{
    const int isF32 = *dtf;
    const int idx = blockIdx.x * 256 + threadIdx.x;
    const int c = idx & 127;
    const float invM = 1.f / (float)MTOT;
    float mean = stats[c] * invM;
    float var  = stats[128 + c] * invM - mean * mean;
    float gam = ld_ext(gammav, c, isF32);
    float bet = ld_ext(betav, c, isF32);
    float g = (float)gi[idx];
    float zn = (g - mean) * rsqrtf(var + 1e-5f) * gam + bet;
    float z = 1.f / (1.f + __expf(-zn));
    float s = (float)sp[idx], t = (float)tp[idx];
    float r = z * s + (1.f - z) * t;
    if (isF32) ((float*)outv)[idx] = r;
    else       ((bf16*)outv)[idx] = (bf16)r;
}

extern "C" void kernel_launch(void* const* d_in, const int* in_sizes, int n_in,
                              void* d_out, int out_size, void* d_ws, size_t ws_size,
                              hipStream_t stream)
{
    const void* hidden = d_in[1];
    const void* tXin   = d_in[2];
    const void* sq_w = d_in[3];  const void* sq_b = d_in[4];
    const void* sk_w = d_in[5];  const void* sk_b = d_in[6];
    const void* sv_w = d_in[7];  const void* sv_b = d_in[8];
    const void* so_w = d_in[9];  const void* so_b = d_in[10];
    const void* tq_w = d_in[11]; const void* tq_b = d_in[12];
    const void* tk_w = d_in[13]; const void* tk_b = d_in[14];
    const void* tv_w = d_in[15]; const void* tv_b = d_in[16];
    const void* to_w = d_in[17]; const void* to_b = d_in[18];
    const void* gate_w = d_in[19]; const void* gate_b = d_in[20];
    const void* gamma  = d_in[21]; const void* beta   = d_in[22];

    // ---- workspace layout ----
    char* ws = (char*)d_ws;
    float* stats = (float*)ws;                        // 1 KB
    int*  dtf    = (int*)(ws + 1024);
    bf16* bB     = (bf16*)(ws + 2048);                // 1664 bf16
    bf16* wT     = (bf16*)(ws + 8192);                // 393216 bf16
    bf16* spaceO = (bf16*)(ws + 794624);              // M*128
    bf16* attnO  = (bf16*)(ws + 21143552);            // M*128 (tempO in-place)
    bf16* QKV    = (bf16*)(ws + 41492480);            // M*640, ends 143,237,120
    bf16* hb     = (bf16*)(ws + 143237120);           // M*128 (only if wsBig)
    bf16* tb     = (bf16*)(ws + 163586048);           // M*128, ends 183,934,976
    bf16* tempO  = attnO;
    bf16* gi     = QKV;                               // alias; QKV dead by gate time

    const int wsBig = (ws_size >= 184000000ull);

    bf16* sW  = wT;            bf16* tW  = wT + 163840;
    bf16* soT = wT + 327680;   bf16* toT = wT + 344064;
    bf16* gwT = wT + 360448;

    hipMemsetAsync(stats, 0, 1024, stream);
    detect_dtype<<<1, 256, 0, stream>>>(hidden, dtf);
    prep_weights<<<dim3(1537), 256, 0, stream>>>(
        sq_w, sk_w, sv_w, so_w, tq_w, tk_w, tv_w, to_w, gate_w,
        sq_b, sk_b, sv_b, so_b, tq_b, tk_b, tv_b, to_b, gate_b,
        wT, bB, dtf);
    if (wsBig)
        cvt_inputs<<<dim3(4968, 2), 256, 0, stream>>>(hidden, tXin, hb, tb, dtf);

    const void* A0 = wsBig ? (const void*)hb : hidden;
    const void* A1 = wsBig ? (const void*)tb : tXin;
    const int aExt = wsBig ? 0 : 1;

    // ---- spatial branch ----
    gemm_bt<<<dim3(621, 5), 256, 0, stream>>>(A0, A1, sW, bB, QKV, 640, 256, 1, aExt, dtf);
    attn_spatial_mfma<<<dim3(8, TDIM, 16), 256, 0, stream>>>(QKV, attnO);
    gemm_bt<<<dim3(621, 1), 256, 0, stream>>>(attnO, nullptr, soT, bB + 1280, spaceO, 128, 128, 1, 0, dtf);

    // ---- temporal branch ----
    gemm_bt<<<dim3(621, 5), 256, 0, stream>>>(A0, A1, tW, bB + 640, QKV, 640, 256, 1, aExt, dtf);
    attn_temporal_mfma<<<dim3(16 * NDIM), 256, 0, stream>>>(QKV, attnO);
    gemm_bt<<<dim3(621, 1), 256, 0, stream>>>(attnO, nullptr, toT, bB + 1408, tempO, 128, 128, 1, 0, dtf);

    // ---- gate + BN + blend ----
    gemm_bt<<<dim3(621, 1), 256, 0, stream>>>(spaceO, tempO, gwT, bB + 1536, gi, 128, 256, 0, 0, dtf);
    bn_stats<<<dim3(621), 256, 0, stream>>>(gi, stats);
    bn_final<<<dim3(39744), 256, 0, stream>>>(gi, spaceO, tempO, gamma, beta, stats, d_out, dtf);
}